// Round 1
// baseline (374.475 us; speedup 1.0000x reference)
//
#include <hip/hip_runtime.h>
#include <stdint.h>

// CIN layers: Xn[b,h,d] = sum_{j,k} W[h,j,k] * X0[b,j,d] * Xi[b,k,d] + bias[h]
// y[d,h] = sum_k Xi*W (mfma_32x32x16, A rows m=b'*16+d, B cols=32h), then
// Xacc += x0[b,j,d]*y.
// R11: counters showed MfmaUtil 35% / VALUBusy 36% / LDS ~36% / occ 21% —
// nothing saturated => latency/lockstep-bound, not throughput-bound. The
// per-stage __syncthreads (needed only to publish the W LDS stage) forced a
// vmcnt(0)+lgkmcnt(0) drain and 4-wave lockstep every 4KB of W. W is L2/L1-hot
// (all 128 b-blocks per ht stream the same bytes), so this version loads W
// fragments straight from global into registers (SGPR base + lane*16 voffset,
// imm offsets 0..3KB), ping-pong double-buffered one stage ahead. Main loop
// now has ZERO barriers; x0s LDS is read-only after one initial barrier.
// Also removes W LDS reads (-33% LDS traffic) and DMA addressing VALU.
// launch_bounds(256,2): ~200 unified regs expected, no spill.
// Grid: 512 blocks = 128 b-groups x 4 h-tiles; block = 4 waves x 8 b x 32 h.

#define NB_F0 39
#define NB_H  128
#define NB_B  4096

typedef float f32x4  __attribute__((ext_vector_type(4)));
typedef float f32x16 __attribute__((ext_vector_type(16)));
typedef short s16x8  __attribute__((ext_vector_type(8)));

__device__ __forceinline__ unsigned short rne_bf16(float f) {
  union { float f; unsigned u; } v; v.f = f;
  return (unsigned short)((v.u + 0x7fffu + ((v.u >> 16) & 1u)) >> 16);
}
__device__ __forceinline__ float bf16_to_f32(unsigned short s) {
  union { unsigned u; float f; } v; v.u = ((unsigned)s) << 16;
  return v.f;
}

// X0 f32 [B][39][16] -> X0T bf16 [B][16][64] (k=j zero-padded, layer-0 A source)
//                    -> X0c bf16 [B][39][16] with d-PERMUTED inner dim
//   (pos<->d swap bits 2,3) so a lane's 8 x0 factors for MFMA regs r=0..7
//   (d = (r&3)+8*((r>>2)&1)+4L) are one contiguous 16B run.
__global__ void prep_x0_kernel(const float* __restrict__ X0g,
                               unsigned short* __restrict__ X0T,
                               unsigned short* __restrict__ X0c) {
  const int b = blockIdx.x;
  const int t = threadIdx.x;
  {
    const int d  = t >> 4;
    const int k4 = (t & 15) << 2;
    unsigned short vv[4];
#pragma unroll
    for (int i = 0; i < 4; ++i) {
      const int k = k4 + i;
      vv[i] = (k < NB_F0) ? rne_bf16(X0g[(size_t)b * (NB_F0 * 16) + k * 16 + d])
                          : (unsigned short)0;
    }
    ushort4 pk; pk.x = vv[0]; pk.y = vv[1]; pk.z = vv[2]; pk.w = vv[3];
    *(ushort4*)&X0T[((size_t)b * 16 + d) * 64 + k4] = pk;
  }
  for (int idx = t; idx < NB_F0 * 16; idx += 256) {
    const int j = idx >> 4, pos = idx & 15;
    const int d = (pos & 3) | (((pos >> 3) & 1) << 2) | (((pos >> 2) & 1) << 3);
    X0c[(size_t)b * (NB_F0 * 16) + idx] =
        rne_bf16(X0g[(size_t)b * (NB_F0 * 16) + j * 16 + d]);
  }
}

// W f32 [128][39*Fi] -> Wf bf16 fragment-linear for 32x32x16 B-operand:
//   Wf[(((j*4 + t)*KC16 + c)*64 + lane)*8 + i]
//     = W[h = t*32 + (lane&31)][j, k = c*16 + (lane>>5)*8 + i]   (0 if k>=Fi)
__global__ void prep_w_kernel(const float* __restrict__ Wsrc,
                              unsigned short* __restrict__ Wdst,
                              int Fi, int kshift, int total) {
  int idx = blockIdx.x * 256 + threadIdx.x;
  if (idx >= total) return;
  const int i    = idx & 7;
  const int lane = (idx >> 3) & 63;
  const int c    = (idx >> 9) & ((1 << kshift) - 1);
  const int jt   = idx >> (9 + kshift);
  const int t    = jt & 3;
  const int j    = jt >> 2;
  const int h = t * 32 + (lane & 31);
  const int k = c * 16 + ((lane >> 5) << 3) + i;
  unsigned short v = 0;
  if (k < Fi) v = rne_bf16(Wsrc[(size_t)h * (NB_F0 * Fi) + j * Fi + k]);
  Wdst[idx] = v;
}

template <int FI_PAD, bool STORE_XN>
__global__ __launch_bounds__(256, 2) void cin_layer(
    const unsigned short* __restrict__ Wf,   // fragment-linear W (see prep)
    const unsigned short* __restrict__ XiT,  // [B][16][FI_PAD] bf16
    const unsigned short* __restrict__ X0c,  // [B][39][16] bf16, d-permuted
    const float* __restrict__ bias,          // [128]
    unsigned short* __restrict__ XnT,        // [B][16][128] bf16 (or unused)
    float* __restrict__ outp)                // d_out + layer*128, stride 384
{
  constexpr int KPASS = FI_PAD / 64;   // 1 or 2 K-passes of 64
  constexpr int KC16  = FI_PAD / 16;   // 16-wide k-chunks total
  constexpr int S     = NB_F0 * KPASS;

  __shared__ __attribute__((aligned(16))) unsigned short x0s[32 * NB_F0 * 16];

  const int tid  = threadIdx.x;
  const int lane = tid & 63;
  const int wv   = tid >> 6;
  const int L    = lane >> 5;       // k-half selector
  const int col  = lane & 31;       // A row m / B col
  const int ht   = blockIdx.x >> 7;            // 0..3 (32 h each)
  const int bblk = (blockIdx.x & 127) * 32;    // 32 b per block
  const int bwave = bblk + wv * 8;             // 8 b per wave

  // ---- stage x0 factors (bf16 d-permuted, flat coalesced copy) ----
  {
    const unsigned short* src = X0c + (size_t)bblk * (NB_F0 * 16);
    for (int c = tid; c < (32 * NB_F0 * 16) / 8; c += 256)
      *(s16x8*)&x0s[c * 8] = *(const s16x8*)&src[c * 8];
  }

  // ---- Xi A-fragments: chain P covers b' = 2P + (col>>4); resident regs ----
  s16x8 af[4][4];
  auto load_af = [&](int pass) {
#pragma unroll
    for (int P = 0; P < 4; ++P) {
      const unsigned short* base = XiT +
          ((size_t)(bwave + 2 * P + (col >> 4)) * 16 + (col & 15)) * FI_PAD +
          pass * 64 + L * 8;
#pragma unroll
      for (int c = 0; c < 4; ++c) af[P][c] = *(const s16x8*)(base + c * 16);
    }
  };
  load_af(0);

  f32x16 Xacc[4], kZero;
#pragma unroll
  for (int r = 0; r < 16; ++r) kZero[r] = 0.f;
#pragma unroll
  for (int P = 0; P < 4; ++P) Xacc[P] = kZero;

  __syncthreads();   // publish x0s; the ONLY barrier in this kernel

  const int x0base = (wv * 8) * (NB_F0 * 16) + L * 8;

  // ---- W fragments straight from global (L2/L1-hot) into registers ----
  // frag(s, cc) at Wf8[((j*4+ht)*KC16 + pass*4 + cc)*64 + lane]; cc stride is
  // 1KB -> SGPR base + lane*16 voffset + imm offsets 0/1024/2048/3072.
  const s16x8* __restrict__ Wf8 = (const s16x8*)Wf;
  auto wload = [&](int s, s16x8 (&w)[4]) {
    const int pass = (KPASS == 2 && s >= NB_F0) ? 1 : 0;
    const int j = s - pass * NB_F0;
    const s16x8* p = Wf8 + ((j * 4 + ht) * KC16 + pass * 4) * 64 + lane;
#pragma unroll
    for (int cc = 0; cc < 4; ++cc) w[cc] = p[cc * 64];
  };

  auto compute = [&](int s, const s16x8 (&w)[4]) {
    if (KPASS == 2 && s == NB_F0) load_af(1);   // af K-window switch
    const int j = (KPASS == 2 && s >= NB_F0) ? s - NB_F0 : s;
    const unsigned short* xr = &x0s[x0base + j * 16];
#pragma unroll
    for (int P = 0; P < 4; ++P) {
      f32x16 y;
      y = __builtin_amdgcn_mfma_f32_32x32x16_bf16(af[P][0], w[0], kZero, 0, 0, 0);
      y = __builtin_amdgcn_mfma_f32_32x32x16_bf16(af[P][1], w[1], y, 0, 0, 0);
      y = __builtin_amdgcn_mfma_f32_32x32x16_bf16(af[P][2], w[2], y, 0, 0, 0);
      y = __builtin_amdgcn_mfma_f32_32x32x16_bf16(af[P][3], w[3], y, 0, 0, 0);

      // x0 scale: regs 0-7 <- b'=2P (this lane's L 8-run), 8-15 <- b'=2P+1.
      // Unpack packed bf16 dwords to f32 pairs; elementwise_fma -> v_pk_fma_f32.
      const uint4 xu0 = *(const uint4*)(xr + (2 * P + 0) * (NB_F0 * 16));
      const uint4 xu1 = *(const uint4*)(xr + (2 * P + 1) * (NB_F0 * 16));
      f32x16 xsc;
      xsc[0]  = __uint_as_float(xu0.x << 16);
      xsc[1]  = __uint_as_float(xu0.x & 0xffff0000u);
      xsc[2]  = __uint_as_float(xu0.y << 16);
      xsc[3]  = __uint_as_float(xu0.y & 0xffff0000u);
      xsc[4]  = __uint_as_float(xu0.z << 16);
      xsc[5]  = __uint_as_float(xu0.z & 0xffff0000u);
      xsc[6]  = __uint_as_float(xu0.w << 16);
      xsc[7]  = __uint_as_float(xu0.w & 0xffff0000u);
      xsc[8]  = __uint_as_float(xu1.x << 16);
      xsc[9]  = __uint_as_float(xu1.x & 0xffff0000u);
      xsc[10] = __uint_as_float(xu1.y << 16);
      xsc[11] = __uint_as_float(xu1.y & 0xffff0000u);
      xsc[12] = __uint_as_float(xu1.z << 16);
      xsc[13] = __uint_as_float(xu1.z & 0xffff0000u);
      xsc[14] = __uint_as_float(xu1.w << 16);
      xsc[15] = __uint_as_float(xu1.w & 0xffff0000u);
      Xacc[P] = __builtin_elementwise_fma(xsc, y, Xacc[P]);
    }
  };

  // ---- barrier-free main loop: ping-pong W regs, prefetch 1 stage ahead ----
  s16x8 wA[4], wB[4];
  wload(0, wA);
  int s = 0;
  for (; s + 2 <= S; s += 2) {
    wload(s + 1, wB);      // issue-early: lands under compute(s)
    compute(s, wA);
    if (s + 2 < S) wload(s + 2, wA);
    compute(s + 1, wB);
  }
  if (s < S) compute(s, wA);   // odd-S tail (layer 0: S=39)

  // ---- epilogue ----
  const float bias_v = bias[ht * 32 + col];
#pragma unroll
  for (int P = 0; P < 4; ++P) {
#pragma unroll
    for (int bh = 0; bh < 2; ++bh) {
      const int b = bwave + 2 * P + bh;
      float v[8];
#pragma unroll
      for (int m = 0; m < 8; ++m) v[m] = Xacc[P][bh * 8 + m] + bias_v;
      if (STORE_XN) {
#pragma unroll
        for (int m = 0; m < 8; ++m) {
          const int d = (m & 3) + 8 * ((m >> 2) & 1) + 4 * L;
          XnT[((size_t)b * 16 + d) * NB_H + ht * 32 + col] = rne_bf16(v[m]);
        }
      }
      float tot = ((v[0] + v[1]) + (v[2] + v[3])) + ((v[4] + v[5]) + (v[6] + v[7]));
      tot += __shfl_xor(tot, 32);
      if (lane < 32) outp[(size_t)b * 384 + ht * 32 + lane] = tot;
    }
  }
}

extern "C" void kernel_launch(void* const* d_in, const int* in_sizes, int n_in,
                              void* d_out, int out_size, void* d_ws, size_t ws_size,
                              hipStream_t stream) {
  (void)in_sizes; (void)n_in; (void)out_size; (void)ws_size;
  const float* X0g = (const float*)d_in[0];
  const float* W0  = (const float*)d_in[1];
  const float* b0  = (const float*)d_in[2];
  const float* W1  = (const float*)d_in[3];
  const float* b1  = (const float*)d_in[4];
  const float* W2  = (const float*)d_in[5];
  const float* b2  = (const float*)d_in[6];
  float* out = (float*)d_out;

  char* p = (char*)d_ws;
  unsigned short* X0T = (unsigned short*)p; p += (size_t)NB_B * 16 * 64 * 2;
  unsigned short* X0c = (unsigned short*)p; p += (size_t)NB_B * NB_F0 * 16 * 2;
  unsigned short* X1T = (unsigned short*)p; p += (size_t)NB_B * 16 * 128 * 2;
  unsigned short* X2T = (unsigned short*)p; p += (size_t)NB_B * 16 * 128 * 2;
  unsigned short* Wf0 = (unsigned short*)p; p += (size_t)NB_F0 * 4 * 4 * 512 * 2;
  unsigned short* Wf1 = (unsigned short*)p; p += (size_t)NB_F0 * 4 * 8 * 512 * 2;
  unsigned short* Wf2 = (unsigned short*)p; p += (size_t)NB_F0 * 4 * 8 * 512 * 2;

  hipLaunchKernelGGL(prep_x0_kernel, dim3(NB_B), dim3(256), 0, stream,
                     X0g, X0T, X0c);
  const int tw0  = NB_F0 * 4 * 4 * 512;   // KC16=4
  const int tw12 = NB_F0 * 4 * 8 * 512;   // KC16=8
  hipLaunchKernelGGL(prep_w_kernel, dim3((tw0 + 255) / 256), dim3(256), 0, stream,
                     W0, Wf0, 39, 2, tw0);
  hipLaunchKernelGGL(prep_w_kernel, dim3((tw12 + 255) / 256), dim3(256), 0, stream,
                     W1, Wf1, 128, 3, tw12);
  hipLaunchKernelGGL(prep_w_kernel, dim3((tw12 + 255) / 256), dim3(256), 0, stream,
                     W2, Wf2, 128, 3, tw12);

  hipLaunchKernelGGL((cin_layer<64, true>),   dim3(512), dim3(256), 0, stream,
                     Wf0, X0T, X0c, b0, X1T, out + 0);
  hipLaunchKernelGGL((cin_layer<128, true>),  dim3(512), dim3(256), 0, stream,
                     Wf1, X1T, X0c, b1, X2T, out + 128);
  hipLaunchKernelGGL((cin_layer<128, false>), dim3(512), dim3(256), 0, stream,
                     Wf2, X2T, X0c, b2, (unsigned short*)nullptr, out + 256);
}

// Round 2
// 323.487 us; speedup vs baseline: 1.1576x; 1.1576x over previous
//
#include <hip/hip_runtime.h>
#include <stdint.h>

// CIN layers: Xn[b,h,d] = sum_{j,k} W[h,j,k] * X0[b,j,d] * Xi[b,k,d] + bias[h]
// y[d,h] = sum_k Xi*W (mfma_32x32x16, A rows m=b'*16+d, B cols=32h), then
// Xacc += x0[b,j,d]*y.
// R11 post-mortem: W-in-registers spilled (VGPR capped 128, WRITE_SIZE 21->77MB
// = scratch traffic) -> 147us/layer. Structure lesson kept, register lesson
// learned: stay with LDS W staging (regs ~108) and remove ONLY the stall.
// R12: T3/T4 counted-vmcnt. Per-stage __syncthreads (implicit vmcnt(0)
// drain of the global_load_lds prefetch) replaced by raw s_barrier +
// s_waitcnt vmcnt(2); W pipeline deepened to 4 buffers / 3-stage prefetch so
// DMAs stay in flight ACROSS barriers. Hazard proof: barrier(s) orders all
// waves past compute(s-1) (ds_reads lgkm-waited before their MFMAs, which
// precede the barrier), so post-barrier DMA into buf[(s+3)&3]==buf[(s-1)&3]
// is race-free; vmcnt(2) before barrier pins own stage-s chunk, barrier
// extends to all waves. Tail issues wrapped dummy DMAs (never read) to keep
// the vmcnt literal constant. Empty memory-clobber asm after the barrier
// blocks ds_read hoisting (rule #18).
// Grid: 512 blocks = 128 b-groups x 4 h-tiles; block = 4 waves x 8 b x 32 h.

#define NB_F0 39
#define NB_H  128
#define NB_B  4096

typedef float f32x4  __attribute__((ext_vector_type(4)));
typedef float f32x16 __attribute__((ext_vector_type(16)));
typedef short s16x8  __attribute__((ext_vector_type(8)));

__device__ __forceinline__ void dma16(const void* g, void* l) {
  __builtin_amdgcn_global_load_lds(
      (const __attribute__((address_space(1))) unsigned int*)g,
      (__attribute__((address_space(3))) unsigned int*)l, 16, 0, 0);
}

__device__ __forceinline__ unsigned short rne_bf16(float f) {
  union { float f; unsigned u; } v; v.f = f;
  return (unsigned short)((v.u + 0x7fffu + ((v.u >> 16) & 1u)) >> 16);
}
__device__ __forceinline__ float bf16_to_f32(unsigned short s) {
  union { unsigned u; float f; } v; v.u = ((unsigned)s) << 16;
  return v.f;
}

// X0 f32 [B][39][16] -> X0T bf16 [B][16][64] (k=j zero-padded, layer-0 A source)
//                    -> X0c bf16 [B][39][16] with d-PERMUTED inner dim
//   (pos<->d swap bits 2,3) so a lane's 8 x0 factors for MFMA regs r=0..7
//   (d = (r&3)+8*((r>>2)&1)+4L) are one contiguous 16B run.
__global__ void prep_x0_kernel(const float* __restrict__ X0g,
                               unsigned short* __restrict__ X0T,
                               unsigned short* __restrict__ X0c) {
  const int b = blockIdx.x;
  const int t = threadIdx.x;
  {
    const int d  = t >> 4;
    const int k4 = (t & 15) << 2;
    unsigned short vv[4];
#pragma unroll
    for (int i = 0; i < 4; ++i) {
      const int k = k4 + i;
      vv[i] = (k < NB_F0) ? rne_bf16(X0g[(size_t)b * (NB_F0 * 16) + k * 16 + d])
                          : (unsigned short)0;
    }
    ushort4 pk; pk.x = vv[0]; pk.y = vv[1]; pk.z = vv[2]; pk.w = vv[3];
    *(ushort4*)&X0T[((size_t)b * 16 + d) * 64 + k4] = pk;
  }
  for (int idx = t; idx < NB_F0 * 16; idx += 256) {
    const int j = idx >> 4, pos = idx & 15;
    const int d = (pos & 3) | (((pos >> 3) & 1) << 2) | (((pos >> 2) & 1) << 3);
    X0c[(size_t)b * (NB_F0 * 16) + idx] =
        rne_bf16(X0g[(size_t)b * (NB_F0 * 16) + j * 16 + d]);
  }
}

// W f32 [128][39*Fi] -> Wf bf16 fragment-linear for 32x32x16 B-operand:
//   Wf[(((j*4 + t)*KC16 + c)*64 + lane)*8 + i]
//     = W[h = t*32 + (lane&31)][j, k = c*16 + (lane>>5)*8 + i]   (0 if k>=Fi)
__global__ void prep_w_kernel(const float* __restrict__ Wsrc,
                              unsigned short* __restrict__ Wdst,
                              int Fi, int kshift, int total) {
  int idx = blockIdx.x * 256 + threadIdx.x;
  if (idx >= total) return;
  const int i    = idx & 7;
  const int lane = (idx >> 3) & 63;
  const int c    = (idx >> 9) & ((1 << kshift) - 1);
  const int jt   = idx >> (9 + kshift);
  const int t    = jt & 3;
  const int j    = jt >> 2;
  const int h = t * 32 + (lane & 31);
  const int k = c * 16 + ((lane >> 5) << 3) + i;
  unsigned short v = 0;
  if (k < Fi) v = rne_bf16(Wsrc[(size_t)h * (NB_F0 * Fi) + j * Fi + k]);
  Wdst[idx] = v;
}

template <int FI_PAD, bool STORE_XN>
__global__ __launch_bounds__(256, 2) void cin_layer(
    const unsigned short* __restrict__ Wf,   // fragment-linear W (see prep)
    const unsigned short* __restrict__ XiT,  // [B][16][FI_PAD] bf16
    const unsigned short* __restrict__ X0c,  // [B][39][16] bf16, d-permuted
    const float* __restrict__ bias,          // [128]
    unsigned short* __restrict__ XnT,        // [B][16][128] bf16 (or unused)
    float* __restrict__ outp)                // d_out + layer*128, stride 384
{
  constexpr int KPASS = FI_PAD / 64;   // 1 or 2 K-passes of 64
  constexpr int KC16  = FI_PAD / 16;   // 16-wide k-chunks total
  constexpr int S     = NB_F0 * KPASS;

  __shared__ __attribute__((aligned(16))) unsigned short Wlds[4][2048]; // 4x4KB
  __shared__ __attribute__((aligned(16))) unsigned short x0s[32 * NB_F0 * 16];

  const int tid  = threadIdx.x;
  const int lane = tid & 63;
  const int wv   = tid >> 6;
  const int L    = lane >> 5;       // k-half selector
  const int col  = lane & 31;       // A row m / B col
  const int ht   = blockIdx.x >> 7;            // 0..3 (32 h each)
  const int bblk = (blockIdx.x & 127) * 32;    // 32 b per block
  const int bwave = bblk + wv * 8;             // 8 b per wave

  // ---- W DMA: wave wv stages chunk wv (1 KB) of the 4 KB stage tile ----
  auto dma_stage = [&](int s, int buf) {
    const int pass = (KPASS == 2 && s >= NB_F0) ? 1 : 0;
    const int j = s - pass * NB_F0;
    const unsigned short* src =
        Wf + (((size_t)(j * 4 + ht) * KC16) + pass * 4 + wv) * 512 + lane * 8;
    dma16(src, &Wlds[buf][wv * 512]);   // lane i -> +i*16B: fragment order
  };

  // ---- stage x0 factors (bf16 d-permuted, flat coalesced copy) ----
  {
    const unsigned short* src = X0c + (size_t)bblk * (NB_F0 * 16);
    for (int c = tid; c < (32 * NB_F0 * 16) / 8; c += 256)
      *(s16x8*)&x0s[c * 8] = *(const s16x8*)&src[c * 8];
  }

  // ---- Xi A-fragments: chain P covers b' = 2P + (col>>4); resident regs ----
  s16x8 af[4][4];
  auto load_af = [&](int pass) {
#pragma unroll
    for (int P = 0; P < 4; ++P) {
      const unsigned short* base = XiT +
          ((size_t)(bwave + 2 * P + (col >> 4)) * 16 + (col & 15)) * FI_PAD +
          pass * 64 + L * 8;
#pragma unroll
      for (int c = 0; c < 4; ++c) af[P][c] = *(const s16x8*)(base + c * 16);
    }
  };
  load_af(0);

  f32x16 Xacc[4], kZero;
#pragma unroll
  for (int r = 0; r < 16; ++r) kZero[r] = 0.f;
#pragma unroll
  for (int P = 0; P < 4; ++P) Xacc[P] = kZero;

  // Publish x0s; full drain (also retires x0/af global loads) so vmcnt
  // counting below sees only W DMAs.
  __syncthreads();

  // ---- prologue: 3-deep W prefetch ----
  dma_stage(0, 0);
  dma_stage(1, 1);
  dma_stage(2, 2);

  const int x0base = (wv * 8) * (NB_F0 * 16) + L * 8;

  auto body = [&](int s) {
    // Counted wait: outstanding DMAs are stages s, s+1, s+2 -> vmcnt(2)
    // retires stage s (own chunk); barrier extends to all waves' chunks.
    asm volatile("s_waitcnt vmcnt(2)" ::: "memory");
    __builtin_amdgcn_s_barrier();
    asm volatile("" ::: "memory");   // fence: no ds_read hoist above barrier

    // Prefetch stage s+3 into buf[(s+3)&3] == buf[(s-1)&3]; safe: all waves
    // are past barrier(s), i.e. done reading stage s-1. Tail wraps to a
    // dummy refetch (target buffer never read again) to keep vmcnt exact.
    const int sn = s + 3;
    dma_stage(sn < S ? sn : sn - S, sn & 3);

    const int j = (KPASS == 2 && s >= NB_F0) ? s - NB_F0 : s;
    const unsigned short* wb = &Wlds[s & 3][lane * 8];
    const s16x8 w0 = *(const s16x8*)(wb);
    const s16x8 w1 = *(const s16x8*)(wb + 512);
    const s16x8 w2 = *(const s16x8*)(wb + 1024);
    const s16x8 w3 = *(const s16x8*)(wb + 1536);

#pragma unroll
    for (int P = 0; P < 4; ++P) {
      f32x16 y;
      y = __builtin_amdgcn_mfma_f32_32x32x16_bf16(af[P][0], w0, kZero, 0, 0, 0);
      y = __builtin_amdgcn_mfma_f32_32x32x16_bf16(af[P][1], w1, y, 0, 0, 0);
      y = __builtin_amdgcn_mfma_f32_32x32x16_bf16(af[P][2], w2, y, 0, 0, 0);
      y = __builtin_amdgcn_mfma_f32_32x32x16_bf16(af[P][3], w3, y, 0, 0, 0);

      // x0 scale: regs 0-7 <- b'=2P (this lane's L 8-run), 8-15 <- b'=2P+1.
      // Unpack packed bf16 dwords to f32 pairs; elementwise_fma -> v_pk_fma_f32.
      const uint4 xu0 = *(const uint4*)
          &x0s[x0base + (2 * P + 0) * (NB_F0 * 16) + j * 16];
      const uint4 xu1 = *(const uint4*)
          &x0s[x0base + (2 * P + 1) * (NB_F0 * 16) + j * 16];
      const unsigned wd[8] = {xu0.x, xu0.y, xu0.z, xu0.w,
                              xu1.x, xu1.y, xu1.z, xu1.w};
      f32x16 xsc;
#pragma unroll
      for (int i = 0; i < 8; ++i) {
        xsc[2 * i]     = __uint_as_float(wd[i] << 16);
        xsc[2 * i + 1] = __uint_as_float(wd[i] & 0xffff0000u);
      }
      Xacc[P] = __builtin_elementwise_fma(xsc, y, Xacc[P]);
    }
  };

  int s = 0;
  for (; s < NB_F0; ++s) body(s);
  if (KPASS == 2) {
    load_af(1);                      // af K-window switch (one-time hiccup:
    for (; s < S; ++s) body(s);      // next vmcnt(2) also drains these loads)
  }

  // ---- epilogue ----
  const float bias_v = bias[ht * 32 + col];
#pragma unroll
  for (int P = 0; P < 4; ++P) {
#pragma unroll
    for (int bh = 0; bh < 2; ++bh) {
      const int b = bwave + 2 * P + bh;
      float v[8];
#pragma unroll
      for (int m = 0; m < 8; ++m) v[m] = Xacc[P][bh * 8 + m] + bias_v;
      if (STORE_XN) {
#pragma unroll
        for (int m = 0; m < 8; ++m) {
          const int d = (m & 3) + 8 * ((m >> 2) & 1) + 4 * L;
          XnT[((size_t)b * 16 + d) * NB_H + ht * 32 + col] = rne_bf16(v[m]);
        }
      }
      float tot = ((v[0] + v[1]) + (v[2] + v[3])) + ((v[4] + v[5]) + (v[6] + v[7]));
      tot += __shfl_xor(tot, 32);
      if (lane < 32) outp[(size_t)b * 384 + ht * 32 + lane] = tot;
    }
  }
}

extern "C" void kernel_launch(void* const* d_in, const int* in_sizes, int n_in,
                              void* d_out, int out_size, void* d_ws, size_t ws_size,
                              hipStream_t stream) {
  (void)in_sizes; (void)n_in; (void)out_size; (void)ws_size;
  const float* X0g = (const float*)d_in[0];
  const float* W0  = (const float*)d_in[1];
  const float* b0  = (const float*)d_in[2];
  const float* W1  = (const float*)d_in[3];
  const float* b1  = (const float*)d_in[4];
  const float* W2  = (const float*)d_in[5];
  const float* b2  = (const float*)d_in[6];
  float* out = (float*)d_out;

  char* p = (char*)d_ws;
  unsigned short* X0T = (unsigned short*)p; p += (size_t)NB_B * 16 * 64 * 2;
  unsigned short* X0c = (unsigned short*)p; p += (size_t)NB_B * NB_F0 * 16 * 2;
  unsigned short* X1T = (unsigned short*)p; p += (size_t)NB_B * 16 * 128 * 2;
  unsigned short* X2T = (unsigned short*)p; p += (size_t)NB_B * 16 * 128 * 2;
  unsigned short* Wf0 = (unsigned short*)p; p += (size_t)NB_F0 * 4 * 4 * 512 * 2;
  unsigned short* Wf1 = (unsigned short*)p; p += (size_t)NB_F0 * 4 * 8 * 512 * 2;
  unsigned short* Wf2 = (unsigned short*)p; p += (size_t)NB_F0 * 4 * 8 * 512 * 2;

  hipLaunchKernelGGL(prep_x0_kernel, dim3(NB_B), dim3(256), 0, stream,
                     X0g, X0T, X0c);
  const int tw0  = NB_F0 * 4 * 4 * 512;   // KC16=4
  const int tw12 = NB_F0 * 4 * 8 * 512;   // KC16=8
  hipLaunchKernelGGL(prep_w_kernel, dim3((tw0 + 255) / 256), dim3(256), 0, stream,
                     W0, Wf0, 39, 2, tw0);
  hipLaunchKernelGGL(prep_w_kernel, dim3((tw12 + 255) / 256), dim3(256), 0, stream,
                     W1, Wf1, 128, 3, tw12);
  hipLaunchKernelGGL(prep_w_kernel, dim3((tw12 + 255) / 256), dim3(256), 0, stream,
                     W2, Wf2, 128, 3, tw12);

  hipLaunchKernelGGL((cin_layer<64, true>),   dim3(512), dim3(256), 0, stream,
                     Wf0, X0T, X0c, b0, X1T, out + 0);
  hipLaunchKernelGGL((cin_layer<128, true>),  dim3(512), dim3(256), 0, stream,
                     Wf1, X1T, X0c, b1, X2T, out + 128);
  hipLaunchKernelGGL((cin_layer<128, false>), dim3(512), dim3(256), 0, stream,
                     Wf2, X2T, X0c, b2, (unsigned short*)nullptr, out + 256);
}

// Round 3
// 311.827 us; speedup vs baseline: 1.2009x; 1.0374x over previous
//
#include <hip/hip_runtime.h>
#include <stdint.h>

// CIN layers: Xn[b,h,d] = sum_{j,k} W[h,j,k] * X0[b,j,d] * Xi[b,k,d] + bias[h]
// y[d,h] = sum_k Xi*W (mfma_32x32x16, A rows m=b'*16+d, B cols=32h), then
// Xacc += x0[b,j,d]*y.
// R12 post-mortem: counted-vmcnt landed clean (no spill) but dur 104->116us,
// MfmaUtil 35.8->31.9 => the barrier's vmcnt(0) drain was NOT the bottleneck.
// All pipes sit at ~31% with occupancy pinned at 21% (grid 512 = 2 blocks/CU,
// 2 waves/SIMD): the kernel is latency-bound from too few resident waves, and
// each per-stage barrier locksteps half the CU.
// R13: occupancy 2x. Grid 1024 = 256 b-groups x 4 ht; 4 b/wave (P=2 chains).
// Block LDS = 19.5KB x0 + 16KB W = 36.3KB <= 40KB -> 4 blocks/CU;
// launch_bounds(256,4) (unified reg demand ~110-125 fits 128). 16 waves/CU =
// 4 waves/SIMD, and a barrier now stalls only 1/4 of resident waves; the
// other 3 independent blocks keep MFMA/VALU/LDS fed. Work per block halves
// (total conserved). W LDS amplification/CU-stage 64KB = 512cyc -> ~17us/layer
// floor, still far under target. Counted-vmcnt 4-buffer W pipeline kept.
// Block = 4 waves x 4 b x 32 h.

#define NB_F0 39
#define NB_H  128
#define NB_B  4096

typedef float f32x4  __attribute__((ext_vector_type(4)));
typedef float f32x16 __attribute__((ext_vector_type(16)));
typedef short s16x8  __attribute__((ext_vector_type(8)));

__device__ __forceinline__ void dma16(const void* g, void* l) {
  __builtin_amdgcn_global_load_lds(
      (const __attribute__((address_space(1))) unsigned int*)g,
      (__attribute__((address_space(3))) unsigned int*)l, 16, 0, 0);
}

__device__ __forceinline__ unsigned short rne_bf16(float f) {
  union { float f; unsigned u; } v; v.f = f;
  return (unsigned short)((v.u + 0x7fffu + ((v.u >> 16) & 1u)) >> 16);
}
__device__ __forceinline__ float bf16_to_f32(unsigned short s) {
  union { unsigned u; float f; } v; v.u = ((unsigned)s) << 16;
  return v.f;
}

// X0 f32 [B][39][16] -> X0T bf16 [B][16][64] (k=j zero-padded, layer-0 A source)
//                    -> X0c bf16 [B][39][16] with d-PERMUTED inner dim
//   (pos<->d swap bits 2,3) so a lane's 8 x0 factors for MFMA regs r=0..7
//   (d = (r&3)+8*((r>>2)&1)+4L) are one contiguous 16B run.
__global__ void prep_x0_kernel(const float* __restrict__ X0g,
                               unsigned short* __restrict__ X0T,
                               unsigned short* __restrict__ X0c) {
  const int b = blockIdx.x;
  const int t = threadIdx.x;
  {
    const int d  = t >> 4;
    const int k4 = (t & 15) << 2;
    unsigned short vv[4];
#pragma unroll
    for (int i = 0; i < 4; ++i) {
      const int k = k4 + i;
      vv[i] = (k < NB_F0) ? rne_bf16(X0g[(size_t)b * (NB_F0 * 16) + k * 16 + d])
                          : (unsigned short)0;
    }
    ushort4 pk; pk.x = vv[0]; pk.y = vv[1]; pk.z = vv[2]; pk.w = vv[3];
    *(ushort4*)&X0T[((size_t)b * 16 + d) * 64 + k4] = pk;
  }
  for (int idx = t; idx < NB_F0 * 16; idx += 256) {
    const int j = idx >> 4, pos = idx & 15;
    const int d = (pos & 3) | (((pos >> 3) & 1) << 2) | (((pos >> 2) & 1) << 3);
    X0c[(size_t)b * (NB_F0 * 16) + idx] =
        rne_bf16(X0g[(size_t)b * (NB_F0 * 16) + j * 16 + d]);
  }
}

// W f32 [128][39*Fi] -> Wf bf16 fragment-linear for 32x32x16 B-operand:
//   Wf[(((j*4 + t)*KC16 + c)*64 + lane)*8 + i]
//     = W[h = t*32 + (lane&31)][j, k = c*16 + (lane>>5)*8 + i]   (0 if k>=Fi)
__global__ void prep_w_kernel(const float* __restrict__ Wsrc,
                              unsigned short* __restrict__ Wdst,
                              int Fi, int kshift, int total) {
  int idx = blockIdx.x * 256 + threadIdx.x;
  if (idx >= total) return;
  const int i    = idx & 7;
  const int lane = (idx >> 3) & 63;
  const int c    = (idx >> 9) & ((1 << kshift) - 1);
  const int jt   = idx >> (9 + kshift);
  const int t    = jt & 3;
  const int j    = jt >> 2;
  const int h = t * 32 + (lane & 31);
  const int k = c * 16 + ((lane >> 5) << 3) + i;
  unsigned short v = 0;
  if (k < Fi) v = rne_bf16(Wsrc[(size_t)h * (NB_F0 * Fi) + j * Fi + k]);
  Wdst[idx] = v;
}

template <int FI_PAD, bool STORE_XN>
__global__ __launch_bounds__(256, 4) void cin_layer(
    const unsigned short* __restrict__ Wf,   // fragment-linear W (see prep)
    const unsigned short* __restrict__ XiT,  // [B][16][FI_PAD] bf16
    const unsigned short* __restrict__ X0c,  // [B][39][16] bf16, d-permuted
    const float* __restrict__ bias,          // [128]
    unsigned short* __restrict__ XnT,        // [B][16][128] bf16 (or unused)
    float* __restrict__ outp)                // d_out + layer*128, stride 384
{
  constexpr int KPASS = FI_PAD / 64;   // 1 or 2 K-passes of 64
  constexpr int KC16  = FI_PAD / 16;   // 16-wide k-chunks total
  constexpr int S     = NB_F0 * KPASS;

  __shared__ __attribute__((aligned(16))) unsigned short Wlds[4][2048]; // 4x4KB
  __shared__ __attribute__((aligned(16))) unsigned short x0s[16 * NB_F0 * 16];

  const int tid  = threadIdx.x;
  const int lane = tid & 63;
  const int wv   = tid >> 6;
  const int L    = lane >> 5;       // k-half selector
  const int col  = lane & 31;       // A row m / B col
  const int ht   = blockIdx.x >> 8;            // 0..3 (32 h each)
  const int bblk = (blockIdx.x & 255) * 16;    // 16 b per block
  const int bwave = bblk + wv * 4;             // 4 b per wave

  // ---- W DMA: wave wv stages chunk wv (1 KB) of the 4 KB stage tile ----
  auto dma_stage = [&](int s, int buf) {
    const int pass = (KPASS == 2 && s >= NB_F0) ? 1 : 0;
    const int j = s - pass * NB_F0;
    const unsigned short* src =
        Wf + (((size_t)(j * 4 + ht) * KC16) + pass * 4 + wv) * 512 + lane * 8;
    dma16(src, &Wlds[buf][wv * 512]);   // lane i -> +i*16B: fragment order
  };

  // ---- stage x0 factors (bf16 d-permuted, flat coalesced copy) ----
  {
    const unsigned short* src = X0c + (size_t)bblk * (NB_F0 * 16);
    for (int c = tid; c < (16 * NB_F0 * 16) / 8; c += 256)
      *(s16x8*)&x0s[c * 8] = *(const s16x8*)&src[c * 8];
  }

  // ---- Xi A-fragments: chain P covers b' = 2P + (col>>4); resident regs ----
  s16x8 af[2][4];
  auto load_af = [&](int pass) {
#pragma unroll
    for (int P = 0; P < 2; ++P) {
      const unsigned short* base = XiT +
          ((size_t)(bwave + 2 * P + (col >> 4)) * 16 + (col & 15)) * FI_PAD +
          pass * 64 + L * 8;
#pragma unroll
      for (int c = 0; c < 4; ++c) af[P][c] = *(const s16x8*)(base + c * 16);
    }
  };
  load_af(0);

  f32x16 Xacc[2], kZero;
#pragma unroll
  for (int r = 0; r < 16; ++r) kZero[r] = 0.f;
#pragma unroll
  for (int P = 0; P < 2; ++P) Xacc[P] = kZero;

  // Publish x0s; full drain (also retires x0/af global loads) so vmcnt
  // counting below sees only W DMAs.
  __syncthreads();

  // ---- prologue: 3-deep W prefetch ----
  dma_stage(0, 0);
  dma_stage(1, 1);
  dma_stage(2, 2);

  const int x0base = (wv * 4) * (NB_F0 * 16) + L * 8;

  auto body = [&](int s) {
    // Counted wait: outstanding DMAs are stages s, s+1, s+2 -> vmcnt(2)
    // retires stage s (own chunk); barrier extends to all waves' chunks.
    asm volatile("s_waitcnt vmcnt(2)" ::: "memory");
    __builtin_amdgcn_s_barrier();
    asm volatile("" ::: "memory");   // fence: no ds_read hoist above barrier

    // Prefetch stage s+3 into buf[(s+3)&3] == buf[(s-1)&3]; safe: all waves
    // are past barrier(s), i.e. done reading stage s-1. Tail wraps to a
    // dummy refetch (target buffer never read again) to keep vmcnt exact.
    const int sn = s + 3;
    dma_stage(sn < S ? sn : sn - S, sn & 3);

    const int j = (KPASS == 2 && s >= NB_F0) ? s - NB_F0 : s;
    const unsigned short* wb = &Wlds[s & 3][lane * 8];
    const s16x8 w0 = *(const s16x8*)(wb);
    const s16x8 w1 = *(const s16x8*)(wb + 512);
    const s16x8 w2 = *(const s16x8*)(wb + 1024);
    const s16x8 w3 = *(const s16x8*)(wb + 1536);

#pragma unroll
    for (int P = 0; P < 2; ++P) {
      f32x16 y;
      y = __builtin_amdgcn_mfma_f32_32x32x16_bf16(af[P][0], w0, kZero, 0, 0, 0);
      y = __builtin_amdgcn_mfma_f32_32x32x16_bf16(af[P][1], w1, y, 0, 0, 0);
      y = __builtin_amdgcn_mfma_f32_32x32x16_bf16(af[P][2], w2, y, 0, 0, 0);
      y = __builtin_amdgcn_mfma_f32_32x32x16_bf16(af[P][3], w3, y, 0, 0, 0);

      // x0 scale: regs 0-7 <- b'=2P (this lane's L 8-run), 8-15 <- b'=2P+1.
      // Unpack packed bf16 dwords to f32 pairs; elementwise_fma -> v_pk_fma_f32.
      const uint4 xu0 = *(const uint4*)
          &x0s[x0base + (2 * P + 0) * (NB_F0 * 16) + j * 16];
      const uint4 xu1 = *(const uint4*)
          &x0s[x0base + (2 * P + 1) * (NB_F0 * 16) + j * 16];
      const unsigned wd[8] = {xu0.x, xu0.y, xu0.z, xu0.w,
                              xu1.x, xu1.y, xu1.z, xu1.w};
      f32x16 xsc;
#pragma unroll
      for (int i = 0; i < 8; ++i) {
        xsc[2 * i]     = __uint_as_float(wd[i] << 16);
        xsc[2 * i + 1] = __uint_as_float(wd[i] & 0xffff0000u);
      }
      Xacc[P] = __builtin_elementwise_fma(xsc, y, Xacc[P]);
    }
  };

  int s = 0;
  for (; s < NB_F0; ++s) body(s);
  if (KPASS == 2) {
    load_af(1);                      // af K-window switch (one-time hiccup:
    for (; s < S; ++s) body(s);      // next vmcnt(2) also drains these loads)
  }

  // ---- epilogue ----
  const float bias_v = bias[ht * 32 + col];
#pragma unroll
  for (int P = 0; P < 2; ++P) {
#pragma unroll
    for (int bh = 0; bh < 2; ++bh) {
      const int b = bwave + 2 * P + bh;
      float v[8];
#pragma unroll
      for (int m = 0; m < 8; ++m) v[m] = Xacc[P][bh * 8 + m] + bias_v;
      if (STORE_XN) {
#pragma unroll
        for (int m = 0; m < 8; ++m) {
          const int d = (m & 3) + 8 * ((m >> 2) & 1) + 4 * L;
          XnT[((size_t)b * 16 + d) * NB_H + ht * 32 + col] = rne_bf16(v[m]);
        }
      }
      float tot = ((v[0] + v[1]) + (v[2] + v[3])) + ((v[4] + v[5]) + (v[6] + v[7]));
      tot += __shfl_xor(tot, 32);
      if (lane < 32) outp[(size_t)b * 384 + ht * 32 + lane] = tot;
    }
  }
}

extern "C" void kernel_launch(void* const* d_in, const int* in_sizes, int n_in,
                              void* d_out, int out_size, void* d_ws, size_t ws_size,
                              hipStream_t stream) {
  (void)in_sizes; (void)n_in; (void)out_size; (void)ws_size;
  const float* X0g = (const float*)d_in[0];
  const float* W0  = (const float*)d_in[1];
  const float* b0  = (const float*)d_in[2];
  const float* W1  = (const float*)d_in[3];
  const float* b1  = (const float*)d_in[4];
  const float* W2  = (const float*)d_in[5];
  const float* b2  = (const float*)d_in[6];
  float* out = (float*)d_out;

  char* p = (char*)d_ws;
  unsigned short* X0T = (unsigned short*)p; p += (size_t)NB_B * 16 * 64 * 2;
  unsigned short* X0c = (unsigned short*)p; p += (size_t)NB_B * NB_F0 * 16 * 2;
  unsigned short* X1T = (unsigned short*)p; p += (size_t)NB_B * 16 * 128 * 2;
  unsigned short* X2T = (unsigned short*)p; p += (size_t)NB_B * 16 * 128 * 2;
  unsigned short* Wf0 = (unsigned short*)p; p += (size_t)NB_F0 * 4 * 4 * 512 * 2;
  unsigned short* Wf1 = (unsigned short*)p; p += (size_t)NB_F0 * 4 * 8 * 512 * 2;
  unsigned short* Wf2 = (unsigned short*)p; p += (size_t)NB_F0 * 4 * 8 * 512 * 2;

  hipLaunchKernelGGL(prep_x0_kernel, dim3(NB_B), dim3(256), 0, stream,
                     X0g, X0T, X0c);
  const int tw0  = NB_F0 * 4 * 4 * 512;   // KC16=4
  const int tw12 = NB_F0 * 4 * 8 * 512;   // KC16=8
  hipLaunchKernelGGL(prep_w_kernel, dim3((tw0 + 255) / 256), dim3(256), 0, stream,
                     W0, Wf0, 39, 2, tw0);
  hipLaunchKernelGGL(prep_w_kernel, dim3((tw12 + 255) / 256), dim3(256), 0, stream,
                     W1, Wf1, 128, 3, tw12);
  hipLaunchKernelGGL(prep_w_kernel, dim3((tw12 + 255) / 256), dim3(256), 0, stream,
                     W2, Wf2, 128, 3, tw12);

  hipLaunchKernelGGL((cin_layer<64, true>),   dim3(1024), dim3(256), 0, stream,
                     Wf0, X0T, X0c, b0, X1T, out + 0);
  hipLaunchKernelGGL((cin_layer<128, true>),  dim3(1024), dim3(256), 0, stream,
                     Wf1, X1T, X0c, b1, X2T, out + 128);
  hipLaunchKernelGGL((cin_layer<128, false>), dim3(1024), dim3(256), 0, stream,
                     Wf2, X2T, X0c, b2, (unsigned short*)nullptr, out + 256);
}